// Round 5
// baseline (448.242 us; speedup 1.0000x reference)
//
#include <hip/hip_runtime.h>
#include <hip/hip_bf16.h>

// LocallyConnected2d: y[b,o,h,w] = bias[o,h,w] +
//   sum_{i,kh,kw} xpad[b,i,h+kh,w+kw] * weight[i,o,h,w,kh,kw]
// B=64, CIN=COUT=64, H=W=32, K=3, pad=1, fp32 in/out.
// Round 10: round-7 structure (verified, fused ~85us) minus the Af identity
// round-trip. In the 4-wave o-half kernel wave ll consumes exactly the
// A-frags it produces, and the composed mapping is
//   a_t[lane][j] = scr_role(lane>>4)[j*64 + t*16 + (lane&15)]
// so the consumer reads scr directly into registers: same ONE write-drain +
// 32 u16 reads as round 7, but no Af writes/reads/LDS. Role stripes padded
// to 528 shorts -> the quad-spread read hits 32 distinct banks (conflict-
// free). LDS 72K -> 48.5K -> 3 blocks/CU with NO added serialization
// (round-9's mistake). A-regs pipelined one chunk ahead. B-path verbatim.

#define B_    64
#define HW_   32
#define HP_   34
#define NLOC  1024
#define W_OST 9216u     // floats per o step
#define W_IST 589824u   // floats per i step
#define XT_BYTES  ((size_t)64*HP_*HP_*64*2)          //  9,469,952
#define WS_NEED   (XT_BYTES)
#define SCR_R 528       // shorts per role stripe: 512 + 16 pad (bank spread)

typedef __attribute__((ext_vector_type(8))) short short8;
typedef __attribute__((ext_vector_type(8))) unsigned short ushort8;
typedef __attribute__((ext_vector_type(4))) float floatx4;

static __device__ __forceinline__ unsigned short f2bf(float f) {
  __hip_bfloat16 h = __float2bfloat16(f);   // RNE
  return __builtin_bit_cast(unsigned short, h);
}

// soft workgroup barrier: drain LDS only, keep VMEM loads in flight
static __device__ __forceinline__ void soft_barrier() {
  __asm__ volatile("s_waitcnt lgkmcnt(0)" ::: "memory");
  __builtin_amdgcn_s_barrier();
}

// ---------------------------------------------------------------------------
// Kernel 1: pad+transpose x[b][i][h][w] (fp32) -> xt[i][hh][ww][b] (bf16).
// (verified rounds 2-7, unchanged)
// ---------------------------------------------------------------------------
__global__ __launch_bounds__(256) void xpose_pad(const float* __restrict__ x,
                                                 unsigned short* __restrict__ xt) {
  int bid = blockIdx.x;                 // 64*34
  int i = bid / HP_, hh = bid % HP_;
  __shared__ float tile[B_ * 33];
  int t = threadIdx.x;
  bool interior = (hh >= 1 && hh <= HW_);
  if (interior) {
    int h = hh - 1, w = t & 31, bs = t >> 5;
    #pragma unroll
    for (int r = 0; r < 8; ++r) {
      int b = r * 8 + bs;
      tile[b * 33 + w] = x[(((size_t)b * 64 + i) * HW_ + h) * HW_ + w];
    }
  }
  __syncthreads();
  int b = t & 63, wsb = t >> 6;
  size_t base = (size_t)(i * HP_ + hh) * HP_ * B_;
  #pragma unroll
  for (int s = 0; s < 9; ++s) {
    int ww = s * 4 + wsb;
    if (ww < HP_) {
      float v = 0.f;
      if (interior && ww >= 1 && ww <= HW_) v = tile[b * 33 + (ww - 1)];
      xt[base + (size_t)ww * B_ + b] = f2bf(v);
    }
  }
}

// ---------------------------------------------------------------------------
// Kernel 2: fused im2col + weight-transform + GEMM, o-half split.
// Block = 4 consecutive locs x 32 o's, 256 thr = 4 waves; wave = ll (loc).
// LDS: Bf 2x8K + Bs 16K + scr4 16.5K = 48.5K -> 3 blocks/CU.
// ---------------------------------------------------------------------------
__global__ __launch_bounds__(256, 3) void lc2d_fused(
    const unsigned short* __restrict__ xt,
    const float* __restrict__ wsrc,
    const float* __restrict__ bias,
    float* __restrict__ out) {
  __shared__ __align__(16) unsigned short Bf[2][8 * 64 * 8];   // 2 x 8 KB
  __shared__ __align__(16) unsigned short Bs[16 * 64 * 8];     // 16 KB (kk=8)
  __shared__ __align__(16) unsigned short scr4[4][4 * SCR_R];  // 16.9 KB

  const int bid   = blockIdx.x;                    // 512 blocks
  const int lt    = ((bid & 7) << 6) | (bid >> 3); // XCD-grouped tile id
  const int ohalf = lt & 1;
  const int loc0  = (lt >> 1) << 2;                // loc0 % 4 == 0
  const int tid   = threadIdx.x;
  const int lane  = tid & 63;
  const int ll    = tid >> 6;                      // wave = loc index 0..3
  const int loc   = loc0 + ll;
  const int hblk  = loc >> 5, wblk = loc & 31;
  const int col   = lane & 15;
  const int quad  = lane >> 4;
  const int o_0   = ohalf * 32 + col;              // nt=0 -> o_0, nt=1 -> +16

  floatx4 acc[4][2];
  {
    float b0 = bias[(unsigned)o_0 * 1024u + (unsigned)loc];
    float b1 = bias[(unsigned)(o_0 + 16) * 1024u + (unsigned)loc];
    #pragma unroll
    for (int mt = 0; mt < 4; ++mt) {
      acc[mt][0] = (floatx4){b0, b0, b0, b0};
      acc[mt][1] = (floatx4){b1, b1, b1, b1};
    }
  }

  // ---- weight staging: 1152 float4 per chunk (4i x 32o x 4loc x 9kk)
  //      (verbatim verified round 7)
  floatx4 wa[5], wb[5];                        // depth-2: two named sets
  const bool lastok = (tid < 128);             // round 4: idx 1024..1151
  const size_t wrow = (size_t)loc0 * 9;        // 16B-aligned (loc0 % 4 == 0)
  const unsigned obase = (unsigned)ohalf * 32u;

  auto issueW = [&](int c, floatx4 (&wreg)[5]) {
    const int i0 = c << 2;
    #pragma unroll
    for (int r = 0; r < 5; ++r) {
      if (r < 4 || lastok) {
        int idx = r * 256 + tid;
        int g = idx / 9, p = idx - g * 9;      // granule, float4-pos
        int i = i0 + (g >> 5), o = (int)obase + (g & 31);
        wreg[r] = *(const floatx4*)(wsrc + (size_t)i * W_IST + (size_t)o * W_OST
                                    + wrow + (size_t)(p * 4));
      }
    }
  };
  auto scatterW = [&](int c, floatx4 (&wreg)[5], unsigned short* bfp) {
    const int i0 = c << 2;
    #pragma unroll
    for (int r = 0; r < 5; ++r) {
      if (r < 4 || lastok) {
        int idx = r * 256 + tid;
        int g = idx / 9, p = idx - g * 9;
        int iq = g >> 5, ol = g & 31;
        int ot = ol >> 4, oc = ol & 15;
        int flane = iq * 16 + oc;              // B-frag lane: quad=iq, col=oc
        #pragma unroll
        for (int e = 0; e < 4; ++e) {
          int fi = p * 4 + e;                  // 0..35 within granule
          int lle = fi / 9, kk = fi - lle * 9;
          unsigned short v = f2bf(wreg[r][e]);
          if (kk < 8) {
            bfp[((lle * 2 + ot) * 64 + flane) * 8 + kk] = v;
          } else {                             // kk == 8 -> stash, k' = i&31
            int i = i0 + iq;
            int sc = i >> 5, k2 = i & 31;
            Bs[(((lle * 2 + sc) * 2 + ot) * 64 + (k2 >> 3) * 16 + oc) * 8 + (k2 & 7)] = v;
          }
        }
      }
    }
  };

  // ---- A side: xt load (verbatim round 7) + 4-role scr + direct reg gather
  auto xtLoad = [&](int t, int q) -> ushort8 {
    int i, kh, kw;
    if (t < 16) {
      i = (t << 2) + q;
      int kk = lane >> 3;                      // 0..7
      kh = kk / 3; kw = kk - kh * 3;
    } else {
      i = ((t - 16) << 5) + (q << 3) + (lane >> 3);
      kh = 2; kw = 2;
    }
    return *(const ushort8*)(xt +
        (((unsigned)i * HP_ + (unsigned)(hblk + kh)) * HP_ + (unsigned)(wblk + kw)) * 64u
        + ((unsigned)(lane & 7) << 3));
  };

  // scr stripe content (per role): elem kk*64 + b  (verified round-7 layout;
  // producer lane l writes X[kk=l>>3][b=(l&7)*8+j] at elem l*8+j).
  // Consumer (composed round-7 identity): a_t[lane][j] =
  //   scr_role(lane>>4)[j*64 + t*16 + (lane&15)].
  auto buildA = [&](ushort8 v0, ushort8 v1, ushort8 v2, ushort8 v3,
                    ushort8 &a0, ushort8 &a1, ushort8 &a2, ushort8 &a3) {
    *(ushort8*)&scr4[ll][0 * SCR_R + (lane << 3)] = v0;
    *(ushort8*)&scr4[ll][1 * SCR_R + (lane << 3)] = v1;
    *(ushort8*)&scr4[ll][2 * SCR_R + (lane << 3)] = v2;
    *(ushort8*)&scr4[ll][3 * SCR_R + (lane << 3)] = v3;
    __asm__ volatile("s_waitcnt lgkmcnt(0)" ::: "memory");
    const int rb = (lane >> 4) * SCR_R + (lane & 15);
    #pragma unroll
    for (int j = 0; j < 8; ++j) {
      a0[j] = scr4[ll][rb + j * 64 +  0];
      a1[j] = scr4[ll][rb + j * 64 + 16];
      a2[j] = scr4[ll][rb + j * 64 + 32];
      a3[j] = scr4[ll][rb + j * 64 + 48];
    }
  };

  // ---- MFMA: 4 A-frags (regs) x 2 B-frags (same call order as verified)
  auto doMFMA = [&](ushort8 a0, ushort8 a1, ushort8 a2, ushort8 a3,
                    const unsigned short* bbase, int boff) {
    ushort8 b0 = *(const ushort8*)(bbase + (size_t)((boff + 0) * 64 + lane) * 8);
    ushort8 b1 = *(const ushort8*)(bbase + (size_t)((boff + 1) * 64 + lane) * 8);
    acc[0][0] = __builtin_amdgcn_mfma_f32_16x16x32_bf16(
        __builtin_bit_cast(short8, a0), __builtin_bit_cast(short8, b0), acc[0][0], 0, 0, 0);
    acc[1][0] = __builtin_amdgcn_mfma_f32_16x16x32_bf16(
        __builtin_bit_cast(short8, a1), __builtin_bit_cast(short8, b0), acc[1][0], 0, 0, 0);
    acc[2][0] = __builtin_amdgcn_mfma_f32_16x16x32_bf16(
        __builtin_bit_cast(short8, a2), __builtin_bit_cast(short8, b0), acc[2][0], 0, 0, 0);
    acc[3][0] = __builtin_amdgcn_mfma_f32_16x16x32_bf16(
        __builtin_bit_cast(short8, a3), __builtin_bit_cast(short8, b0), acc[3][0], 0, 0, 0);
    acc[0][1] = __builtin_amdgcn_mfma_f32_16x16x32_bf16(
        __builtin_bit_cast(short8, a0), __builtin_bit_cast(short8, b1), acc[0][1], 0, 0, 0);
    acc[1][1] = __builtin_amdgcn_mfma_f32_16x16x32_bf16(
        __builtin_bit_cast(short8, a1), __builtin_bit_cast(short8, b1), acc[1][1], 0, 0, 0);
    acc[2][1] = __builtin_amdgcn_mfma_f32_16x16x32_bf16(
        __builtin_bit_cast(short8, a2), __builtin_bit_cast(short8, b1), acc[2][1], 0, 0, 0);
    acc[3][1] = __builtin_amdgcn_mfma_f32_16x16x32_bf16(
        __builtin_bit_cast(short8, a3), __builtin_bit_cast(short8, b1), acc[3][1], 0, 0, 0);
  };

  // ---- prologue: chunk 0 A in regs + B staged, chunk 1 weights issued
  issueW(0, wa);
  ushort8 a0, a1, a2, a3;
  {
    ushort8 xv0 = xtLoad(0, 0), xv1 = xtLoad(0, 1);
    ushort8 xv2 = xtLoad(0, 2), xv3 = xtLoad(0, 3);
    scatterW(0, wa, &Bf[0][0]);
    issueW(1, wb);
    buildA(xv0, xv1, xv2, xv3, a0, a1, a2, a3);
  }
  soft_barrier();

  // ---- main loop c = 0..15 (unrolled x2 so wa/wb indexing is static)
#define STEP(C, WI, WS) do {                                                  \
    const int c_ = (C);                                                       \
    ushort8 nx0 = xtLoad(c_ + 1, 0), nx1 = xtLoad(c_ + 1, 1);                 \
    ushort8 nx2 = xtLoad(c_ + 1, 2), nx3 = xtLoad(c_ + 1, 3);                 \
    if (c_ + 2 <= 15) issueW(c_ + 2, WI);                                     \
    doMFMA(a0, a1, a2, a3, &Bf[c_ & 1][0], ll << 1);                          \
    buildA(nx0, nx1, nx2, nx3, a0, a1, a2, a3);  /* A for c_+1 */             \
    if (c_ + 1 <= 15) scatterW(c_ + 1, WS, &Bf[(c_ & 1) ^ 1][0]);             \
    soft_barrier();                                                           \
  } while (0)

  #pragma unroll 1
  for (int cc = 0; cc < 16; cc += 2) {
    STEP(cc,     wa, wb);   // even c: issue->wa, scatter<-wb
    STEP(cc + 1, wb, wa);   // odd  c: issue->wb, scatter<-wa
  }
#undef STEP

  // ---- stash chunks (kk=8): c = 16, 17 (B from Bs, written by chunk<=15
  //      scatters and barrier'd; scr4 wave-private so no barrier needed)
  {
    ushort8 nx0 = xtLoad(17, 0), nx1 = xtLoad(17, 1);
    ushort8 nx2 = xtLoad(17, 2), nx3 = xtLoad(17, 3);
    doMFMA(a0, a1, a2, a3, &Bs[0], (ll << 1) << 1);        // c=16 (sc=0)
    buildA(nx0, nx1, nx2, nx3, a0, a1, a2, a3);            // A for c=17
    doMFMA(a0, a1, a2, a3, &Bs[0], ((ll << 1) + 1) << 1);  // c=17 (sc=1)
  }

  // ---- epilogue: D mapping col=o=lane&15, row=b = mt*16 + quad*4 + r (verified)
  #pragma unroll
  for (int mt = 0; mt < 4; ++mt) {
    int b = mt * 16 + quad * 4;
    #pragma unroll
    for (int r = 0; r < 4; ++r) {
      out[((unsigned)(b + r) * 64u + (unsigned)o_0) * 1024u + (unsigned)loc] = acc[mt][0][r];
      out[((unsigned)(b + r) * 64u + (unsigned)(o_0 + 16)) * 1024u + (unsigned)loc] = acc[mt][1][r];
    }
  }
}

// ---------------------------------------------------------------------------
// Fallback (tiny ws): fp32, direct x reads (round 1, correct for any ws).
// ---------------------------------------------------------------------------
__global__ __launch_bounds__(256, 4) void lc2d_fallback(
    const float* __restrict__ x, const float* __restrict__ weight,
    const float* __restrict__ bias, float* __restrict__ out) {
  int t0 = blockIdx.x;
  int loc = ((t0 & 7) << 7) | (t0 >> 3);
  int h = loc >> 5, w = loc & 31;
  int tid = threadIdx.x;
  int b = tid & 63;
  int o0 = (tid >> 6) * 16;
  __shared__ float As[72 * 64];
  float acc[16];
  #pragma unroll
  for (int j = 0; j < 16; ++j) acc[j] = bias[(size_t)(o0 + j) * NLOC + loc];
  for (int ic = 0; ic < 8; ++ic) {
    __syncthreads();
    #pragma unroll
    for (int s = 0; s < 18; ++s) {
      int f = s * 256 + tid;
      int k = f >> 6, lb = f & 63;
      int kk = k >> 3, isub = k & 7;
      int i = ic * 8 + isub;
      int kh = kk / 3, kw = kk - kh * 3;
      int hh = h + kh - 1, ww = w + kw - 1;
      float v = (hh >= 0 && hh < HW_ && ww >= 0 && ww < HW_)
                  ? x[(((size_t)lb * 64 + i) * HW_ + hh) * HW_ + ww] : 0.f;
      As[k * 64 + lb] = v;
    }
    __syncthreads();
    #pragma unroll 1
    for (int isub = 0; isub < 8; ++isub) {
      const float* wp = weight + (size_t)(ic * 8 + isub) * W_IST
                               + (size_t)o0 * W_OST + loc * 9;
      #pragma unroll
      for (int kk = 0; kk < 9; ++kk) {
        float a = As[(kk * 8 + isub) * 64 + b];
        #pragma unroll
        for (int j = 0; j < 16; ++j)
          acc[j] = fmaf(a, wp[(size_t)j * W_OST + kk], acc[j]);
      }
    }
  }
  size_t ob = ((size_t)b * 64 + o0) * NLOC + loc;
  #pragma unroll
  for (int j = 0; j < 16; ++j) out[ob + (size_t)j * NLOC] = acc[j];
}

// ---------------------------------------------------------------------------
extern "C" void kernel_launch(void* const* d_in, const int* in_sizes, int n_in,
                              void* d_out, int out_size, void* d_ws, size_t ws_size,
                              hipStream_t stream) {
  const float* x  = (const float*)d_in[0];
  const float* wt = (const float*)d_in[1];
  const float* bs = (const float*)d_in[2];
  float* out = (float*)d_out;

  if (ws_size >= WS_NEED) {
    unsigned short* xtb = (unsigned short*)d_ws;
    xpose_pad<<<64 * HP_, 256, 0, stream>>>(x, xtb);
    lc2d_fused<<<512, 256, 0, stream>>>(xtb, wt, bs, out);
  } else {
    lc2d_fallback<<<NLOC, 256, 0, stream>>>(x, wt, bs, out);
  }
}

// Round 6
// 252.469 us; speedup vs baseline: 1.7754x; 1.7754x over previous
//
#include <hip/hip_runtime.h>
#include <hip/hip_bf16.h>

// LocallyConnected2d: y[b,o,h,w] = bias[o,h,w] +
//   sum_{i,kh,kw} xpad[b,i,h+kh,w+kw] * weight[i,o,h,w,kh,kw]
// B=64, CIN=COUT=64, H=W=32, K=3, pad=1, fp32 in/out.
// Round 11: round-10 dataflow (verified correct: scr-direct A gather, no Af)
// with __launch_bounds__(256, 2). Evidence from rounds 9/10: the (256,3)
// bound made the compiler collapse to VGPR 84 < sum of named prefetch regs,
// i.e. it sank the issueW/xtLoad loads to their uses, serializing the
// depth-2 weight pipeline (fused 85 -> 215/280us, VALUBusy 3.6%). With
// (256,2) the compiler keeps loads hoisted (as in the verified 85us kernel);
// LDS 48.5KB still lets the HW run 3 blocks/CU at runtime.

#define B_    64
#define HW_   32
#define HP_   34
#define NLOC  1024
#define W_OST 9216u     // floats per o step
#define W_IST 589824u   // floats per i step
#define XT_BYTES  ((size_t)64*HP_*HP_*64*2)          //  9,469,952
#define WS_NEED   (XT_BYTES)
#define SCR_R 528       // shorts per role stripe: 512 + 16 pad (bank spread)

typedef __attribute__((ext_vector_type(8))) short short8;
typedef __attribute__((ext_vector_type(8))) unsigned short ushort8;
typedef __attribute__((ext_vector_type(4))) float floatx4;

static __device__ __forceinline__ unsigned short f2bf(float f) {
  __hip_bfloat16 h = __float2bfloat16(f);   // RNE
  return __builtin_bit_cast(unsigned short, h);
}

// soft workgroup barrier: drain LDS only, keep VMEM loads in flight
static __device__ __forceinline__ void soft_barrier() {
  __asm__ volatile("s_waitcnt lgkmcnt(0)" ::: "memory");
  __builtin_amdgcn_s_barrier();
}

// ---------------------------------------------------------------------------
// Kernel 1: pad+transpose x[b][i][h][w] (fp32) -> xt[i][hh][ww][b] (bf16).
// (verified rounds 2-7, unchanged)
// ---------------------------------------------------------------------------
__global__ __launch_bounds__(256) void xpose_pad(const float* __restrict__ x,
                                                 unsigned short* __restrict__ xt) {
  int bid = blockIdx.x;                 // 64*34
  int i = bid / HP_, hh = bid % HP_;
  __shared__ float tile[B_ * 33];
  int t = threadIdx.x;
  bool interior = (hh >= 1 && hh <= HW_);
  if (interior) {
    int h = hh - 1, w = t & 31, bs = t >> 5;
    #pragma unroll
    for (int r = 0; r < 8; ++r) {
      int b = r * 8 + bs;
      tile[b * 33 + w] = x[(((size_t)b * 64 + i) * HW_ + h) * HW_ + w];
    }
  }
  __syncthreads();
  int b = t & 63, wsb = t >> 6;
  size_t base = (size_t)(i * HP_ + hh) * HP_ * B_;
  #pragma unroll
  for (int s = 0; s < 9; ++s) {
    int ww = s * 4 + wsb;
    if (ww < HP_) {
      float v = 0.f;
      if (interior && ww >= 1 && ww <= HW_) v = tile[b * 33 + (ww - 1)];
      xt[base + (size_t)ww * B_ + b] = f2bf(v);
    }
  }
}

// ---------------------------------------------------------------------------
// Kernel 2: fused im2col + weight-transform + GEMM, o-half split.
// Block = 4 consecutive locs x 32 o's, 256 thr = 4 waves; wave = ll (loc).
// LDS: Bf 2x8K + Bs 16K + scr4 16.9K = 48.9K -> HW allows 3 blocks/CU.
// ---------------------------------------------------------------------------
__global__ __launch_bounds__(256, 2) void lc2d_fused(
    const unsigned short* __restrict__ xt,
    const float* __restrict__ wsrc,
    const float* __restrict__ bias,
    float* __restrict__ out) {
  __shared__ __align__(16) unsigned short Bf[2][8 * 64 * 8];   // 2 x 8 KB
  __shared__ __align__(16) unsigned short Bs[16 * 64 * 8];     // 16 KB (kk=8)
  __shared__ __align__(16) unsigned short scr4[4][4 * SCR_R];  // 16.9 KB

  const int bid   = blockIdx.x;                    // 512 blocks
  const int lt    = ((bid & 7) << 6) | (bid >> 3); // XCD-grouped tile id
  const int ohalf = lt & 1;
  const int loc0  = (lt >> 1) << 2;                // loc0 % 4 == 0
  const int tid   = threadIdx.x;
  const int lane  = tid & 63;
  const int ll    = tid >> 6;                      // wave = loc index 0..3
  const int loc   = loc0 + ll;
  const int hblk  = loc >> 5, wblk = loc & 31;
  const int col   = lane & 15;
  const int quad  = lane >> 4;
  const int o_0   = ohalf * 32 + col;              // nt=0 -> o_0, nt=1 -> +16

  floatx4 acc[4][2];
  {
    float b0 = bias[(unsigned)o_0 * 1024u + (unsigned)loc];
    float b1 = bias[(unsigned)(o_0 + 16) * 1024u + (unsigned)loc];
    #pragma unroll
    for (int mt = 0; mt < 4; ++mt) {
      acc[mt][0] = (floatx4){b0, b0, b0, b0};
      acc[mt][1] = (floatx4){b1, b1, b1, b1};
    }
  }

  // ---- weight staging: 1152 float4 per chunk (4i x 32o x 4loc x 9kk)
  //      (verbatim verified round 7)
  floatx4 wa[5], wb[5];                        // depth-2: two named sets
  const bool lastok = (tid < 128);             // round 4: idx 1024..1151
  const size_t wrow = (size_t)loc0 * 9;        // 16B-aligned (loc0 % 4 == 0)
  const unsigned obase = (unsigned)ohalf * 32u;

  auto issueW = [&](int c, floatx4 (&wreg)[5]) {
    const int i0 = c << 2;
    #pragma unroll
    for (int r = 0; r < 5; ++r) {
      if (r < 4 || lastok) {
        int idx = r * 256 + tid;
        int g = idx / 9, p = idx - g * 9;      // granule, float4-pos
        int i = i0 + (g >> 5), o = (int)obase + (g & 31);
        wreg[r] = *(const floatx4*)(wsrc + (size_t)i * W_IST + (size_t)o * W_OST
                                    + wrow + (size_t)(p * 4));
      }
    }
  };
  auto scatterW = [&](int c, floatx4 (&wreg)[5], unsigned short* bfp) {
    const int i0 = c << 2;
    #pragma unroll
    for (int r = 0; r < 5; ++r) {
      if (r < 4 || lastok) {
        int idx = r * 256 + tid;
        int g = idx / 9, p = idx - g * 9;
        int iq = g >> 5, ol = g & 31;
        int ot = ol >> 4, oc = ol & 15;
        int flane = iq * 16 + oc;              // B-frag lane: quad=iq, col=oc
        #pragma unroll
        for (int e = 0; e < 4; ++e) {
          int fi = p * 4 + e;                  // 0..35 within granule
          int lle = fi / 9, kk = fi - lle * 9;
          unsigned short v = f2bf(wreg[r][e]);
          if (kk < 8) {
            bfp[((lle * 2 + ot) * 64 + flane) * 8 + kk] = v;
          } else {                             // kk == 8 -> stash, k' = i&31
            int i = i0 + iq;
            int sc = i >> 5, k2 = i & 31;
            Bs[(((lle * 2 + sc) * 2 + ot) * 64 + (k2 >> 3) * 16 + oc) * 8 + (k2 & 7)] = v;
          }
        }
      }
    }
  };

  // ---- A side: xt load (verbatim round 7) + 4-role scr + direct reg gather
  auto xtLoad = [&](int t, int q) -> ushort8 {
    int i, kh, kw;
    if (t < 16) {
      i = (t << 2) + q;
      int kk = lane >> 3;                      // 0..7
      kh = kk / 3; kw = kk - kh * 3;
    } else {
      i = ((t - 16) << 5) + (q << 3) + (lane >> 3);
      kh = 2; kw = 2;
    }
    return *(const ushort8*)(xt +
        (((unsigned)i * HP_ + (unsigned)(hblk + kh)) * HP_ + (unsigned)(wblk + kw)) * 64u
        + ((unsigned)(lane & 7) << 3));
  };

  // scr stripe content (per role): elem kk*64 + b  (verified round-7 layout;
  // producer lane l writes X[kk=l>>3][b=(l&7)*8+j] at elem l*8+j).
  // Consumer (composed round-7 identity): a_t[lane][j] =
  //   scr_role(lane>>4)[j*64 + t*16 + (lane&15)].
  auto buildA = [&](ushort8 v0, ushort8 v1, ushort8 v2, ushort8 v3,
                    ushort8 &a0, ushort8 &a1, ushort8 &a2, ushort8 &a3) {
    *(ushort8*)&scr4[ll][0 * SCR_R + (lane << 3)] = v0;
    *(ushort8*)&scr4[ll][1 * SCR_R + (lane << 3)] = v1;
    *(ushort8*)&scr4[ll][2 * SCR_R + (lane << 3)] = v2;
    *(ushort8*)&scr4[ll][3 * SCR_R + (lane << 3)] = v3;
    __asm__ volatile("s_waitcnt lgkmcnt(0)" ::: "memory");
    const int rb = (lane >> 4) * SCR_R + (lane & 15);
    #pragma unroll
    for (int j = 0; j < 8; ++j) {
      a0[j] = scr4[ll][rb + j * 64 +  0];
      a1[j] = scr4[ll][rb + j * 64 + 16];
      a2[j] = scr4[ll][rb + j * 64 + 32];
      a3[j] = scr4[ll][rb + j * 64 + 48];
    }
  };

  // ---- MFMA: 4 A-frags (regs) x 2 B-frags (same call order as verified)
  auto doMFMA = [&](ushort8 a0, ushort8 a1, ushort8 a2, ushort8 a3,
                    const unsigned short* bbase, int boff) {
    ushort8 b0 = *(const ushort8*)(bbase + (size_t)((boff + 0) * 64 + lane) * 8);
    ushort8 b1 = *(const ushort8*)(bbase + (size_t)((boff + 1) * 64 + lane) * 8);
    acc[0][0] = __builtin_amdgcn_mfma_f32_16x16x32_bf16(
        __builtin_bit_cast(short8, a0), __builtin_bit_cast(short8, b0), acc[0][0], 0, 0, 0);
    acc[1][0] = __builtin_amdgcn_mfma_f32_16x16x32_bf16(
        __builtin_bit_cast(short8, a1), __builtin_bit_cast(short8, b0), acc[1][0], 0, 0, 0);
    acc[2][0] = __builtin_amdgcn_mfma_f32_16x16x32_bf16(
        __builtin_bit_cast(short8, a2), __builtin_bit_cast(short8, b0), acc[2][0], 0, 0, 0);
    acc[3][0] = __builtin_amdgcn_mfma_f32_16x16x32_bf16(
        __builtin_bit_cast(short8, a3), __builtin_bit_cast(short8, b0), acc[3][0], 0, 0, 0);
    acc[0][1] = __builtin_amdgcn_mfma_f32_16x16x32_bf16(
        __builtin_bit_cast(short8, a0), __builtin_bit_cast(short8, b1), acc[0][1], 0, 0, 0);
    acc[1][1] = __builtin_amdgcn_mfma_f32_16x16x32_bf16(
        __builtin_bit_cast(short8, a1), __builtin_bit_cast(short8, b1), acc[1][1], 0, 0, 0);
    acc[2][1] = __builtin_amdgcn_mfma_f32_16x16x32_bf16(
        __builtin_bit_cast(short8, a2), __builtin_bit_cast(short8, b1), acc[2][1], 0, 0, 0);
    acc[3][1] = __builtin_amdgcn_mfma_f32_16x16x32_bf16(
        __builtin_bit_cast(short8, a3), __builtin_bit_cast(short8, b1), acc[3][1], 0, 0, 0);
  };

  // ---- prologue: chunk 0 A in regs + B staged, chunk 1 weights issued
  issueW(0, wa);
  ushort8 a0, a1, a2, a3;
  {
    ushort8 xv0 = xtLoad(0, 0), xv1 = xtLoad(0, 1);
    ushort8 xv2 = xtLoad(0, 2), xv3 = xtLoad(0, 3);
    scatterW(0, wa, &Bf[0][0]);
    issueW(1, wb);
    buildA(xv0, xv1, xv2, xv3, a0, a1, a2, a3);
  }
  soft_barrier();

  // ---- main loop c = 0..15 (unrolled x2 so wa/wb indexing is static)
#define STEP(C, WI, WS) do {                                                  \
    const int c_ = (C);                                                       \
    ushort8 nx0 = xtLoad(c_ + 1, 0), nx1 = xtLoad(c_ + 1, 1);                 \
    ushort8 nx2 = xtLoad(c_ + 1, 2), nx3 = xtLoad(c_ + 1, 3);                 \
    if (c_ + 2 <= 15) issueW(c_ + 2, WI);                                     \
    doMFMA(a0, a1, a2, a3, &Bf[c_ & 1][0], ll << 1);                          \
    buildA(nx0, nx1, nx2, nx3, a0, a1, a2, a3);  /* A for c_+1 */             \
    if (c_ + 1 <= 15) scatterW(c_ + 1, WS, &Bf[(c_ & 1) ^ 1][0]);             \
    soft_barrier();                                                           \
  } while (0)

  #pragma unroll 1
  for (int cc = 0; cc < 16; cc += 2) {
    STEP(cc,     wa, wb);   // even c: issue->wa, scatter<-wb
    STEP(cc + 1, wb, wa);   // odd  c: issue->wb, scatter<-wa
  }
#undef STEP

  // ---- stash chunks (kk=8): c = 16, 17 (B from Bs, written by chunk<=15
  //      scatters and barrier'd; scr4 wave-private so no barrier needed)
  {
    ushort8 nx0 = xtLoad(17, 0), nx1 = xtLoad(17, 1);
    ushort8 nx2 = xtLoad(17, 2), nx3 = xtLoad(17, 3);
    doMFMA(a0, a1, a2, a3, &Bs[0], (ll << 1) << 1);        // c=16 (sc=0)
    buildA(nx0, nx1, nx2, nx3, a0, a1, a2, a3);            // A for c=17
    doMFMA(a0, a1, a2, a3, &Bs[0], ((ll << 1) + 1) << 1);  // c=17 (sc=1)
  }

  // ---- epilogue: D mapping col=o=lane&15, row=b = mt*16 + quad*4 + r (verified)
  #pragma unroll
  for (int mt = 0; mt < 4; ++mt) {
    int b = mt * 16 + quad * 4;
    #pragma unroll
    for (int r = 0; r < 4; ++r) {
      out[((unsigned)(b + r) * 64u + (unsigned)o_0) * 1024u + (unsigned)loc] = acc[mt][0][r];
      out[((unsigned)(b + r) * 64u + (unsigned)(o_0 + 16)) * 1024u + (unsigned)loc] = acc[mt][1][r];
    }
  }
}

// ---------------------------------------------------------------------------
// Fallback (tiny ws): fp32, direct x reads (round 1, correct for any ws).
// ---------------------------------------------------------------------------
__global__ __launch_bounds__(256, 4) void lc2d_fallback(
    const float* __restrict__ x, const float* __restrict__ weight,
    const float* __restrict__ bias, float* __restrict__ out) {
  int t0 = blockIdx.x;
  int loc = ((t0 & 7) << 7) | (t0 >> 3);
  int h = loc >> 5, w = loc & 31;
  int tid = threadIdx.x;
  int b = tid & 63;
  int o0 = (tid >> 6) * 16;
  __shared__ float As[72 * 64];
  float acc[16];
  #pragma unroll
  for (int j = 0; j < 16; ++j) acc[j] = bias[(size_t)(o0 + j) * NLOC + loc];
  for (int ic = 0; ic < 8; ++ic) {
    __syncthreads();
    #pragma unroll
    for (int s = 0; s < 18; ++s) {
      int f = s * 256 + tid;
      int k = f >> 6, lb = f & 63;
      int kk = k >> 3, isub = k & 7;
      int i = ic * 8 + isub;
      int kh = kk / 3, kw = kk - kh * 3;
      int hh = h + kh - 1, ww = w + kw - 1;
      float v = (hh >= 0 && hh < HW_ && ww >= 0 && ww < HW_)
                  ? x[(((size_t)lb * 64 + i) * HW_ + hh) * HW_ + ww] : 0.f;
      As[k * 64 + lb] = v;
    }
    __syncthreads();
    #pragma unroll 1
    for (int isub = 0; isub < 8; ++isub) {
      const float* wp = weight + (size_t)(ic * 8 + isub) * W_IST
                               + (size_t)o0 * W_OST + loc * 9;
      #pragma unroll
      for (int kk = 0; kk < 9; ++kk) {
        float a = As[(kk * 8 + isub) * 64 + b];
        #pragma unroll
        for (int j = 0; j < 16; ++j)
          acc[j] = fmaf(a, wp[(size_t)j * W_OST + kk], acc[j]);
      }
    }
  }
  size_t ob = ((size_t)b * 64 + o0) * NLOC + loc;
  #pragma unroll
  for (int j = 0; j < 16; ++j) out[ob + (size_t)j * NLOC] = acc[j];
}

// ---------------------------------------------------------------------------
extern "C" void kernel_launch(void* const* d_in, const int* in_sizes, int n_in,
                              void* d_out, int out_size, void* d_ws, size_t ws_size,
                              hipStream_t stream) {
  const float* x  = (const float*)d_in[0];
  const float* wt = (const float*)d_in[1];
  const float* bs = (const float*)d_in[2];
  float* out = (float*)d_out;

  if (ws_size >= WS_NEED) {
    unsigned short* xtb = (unsigned short*)d_ws;
    xpose_pad<<<64 * HP_, 256, 0, stream>>>(x, xtb);
    lc2d_fused<<<512, 256, 0, stream>>>(xtb, wt, bs, out);
  } else {
    lc2d_fallback<<<NLOC, 256, 0, stream>>>(x, wt, bs, out);
  }
}